// Round 12
// baseline (249.063 us; speedup 1.0000x reference)
//
#include <hip/hip_runtime.h>
#include <math.h>
#include <float.h>

#define LOUT 4
#define BATCH 4
#define NP 1000
#define NC 80
#define NM 64
#define ND 256
#define TT 784
#define NIMG (LOUT*BATCH)
#define CWTT (NC*TT)   // 62720
#define MAXF (NIMG*NP) // 16000
#define CH 16          // priors per chunk
#define TPT 112        // t-values per tile (7*112 = 784)
#define MAXCH 768      // multiple of 8; >= 640+80 worst-case chunks

__device__ __forceinline__ float block_reduce_sum(float v, float* red) {
    int tid = threadIdx.x;
    red[tid] = v; __syncthreads();
    for (int s = blockDim.x >> 1; s > 0; s >>= 1) {
        if (tid < s) red[tid] += red[tid + s];
        __syncthreads();
    }
    float r = red[0]; __syncthreads();
    return r;
}

// ============ fused prep: gmsum | valid | logT | negsum | zeroing ============
__global__ void __launch_bounds__(256) k_prep(
        const float* __restrict__ logits, const float* __restrict__ boxes,
        const float* __restrict__ gtb, const float* __restrict__ gtm,
        int* __restrict__ valid, unsigned long long* __restrict__ inboth,
        int* __restrict__ hasvalid, float* __restrict__ logT,
        float* __restrict__ negsum, float* __restrict__ gmsum,
        float* __restrict__ interA, float* __restrict__ msumA,
        float* __restrict__ accum, int* __restrict__ cnt) {
    int blk = blockIdx.x;
    int tid = threadIdx.x;
    __shared__ float red[256];
    __shared__ float tile[32][33];
    if (blk < 256) {
        int bj = blk;
        float s = 0.f;
        for (int t = tid; t < TT; t += 256) s += gtm[(size_t)bj * TT + t];
        float r = block_reduce_sum(s, red);
        if (tid == 0) gmsum[bj] = r;
    } else if (blk < 320) {
        int rel = blk - 256;
        int img = rel >> 2, q = rel & 3, b = img % BATCH;
        float* g = red;
        g[tid] = gtb[b * NM * 4 + tid];
        __syncthreads();
        int i = q * 256 + tid;
        if (i >= NP) return;
        float4 bx = *(const float4*)&boxes[((size_t)img * NP + i) * 4];
        float x0 = bx.x, y0 = bx.y, x1 = bx.z, y1 = bx.w;
        float cx = (x0 + x1) * 0.5f, cy = (y0 + y1) * 0.5f;
        float w = x1 - x0, h = y1 - y0;
        float rx = 2.5f * w, ry = 2.5f * h;
        bool any_gt = false, any_ct = false;
        unsigned long long ib = 0ull;
        for (int j = 0; j < NM; ++j) {
            float gx0 = g[j*4], gy0 = g[j*4+1], gx1 = g[j*4+2], gy1 = g[j*4+3];
            bool igt = (cx > gx0) && (cy > gy0) && (cx < gx1) && (cy < gy1);
            float gcx = (gx0 + gx1) * 0.5f, gcy = (gy0 + gy1) * 0.5f;
            bool ict = (cx > gcx - rx) && (cx < gcx + rx) && (cy > gcy - ry) && (cy < gcy + ry);
            any_gt |= igt; any_ct |= ict;
            if (igt && ict) ib |= (1ull << j);
        }
        bool v = any_gt || any_ct;
        valid[img * NP + i] = v ? 1 : 0;
        inboth[img * NP + i] = ib;
        if (v) atomicOr(&hasvalid[img], 1);
    } else if (blk < 1856) {
        int rel = blk - 320;
        int img = rel / 96; int r2 = rel % 96;
        int i0 = (r2 / 3) * 32, c0 = (r2 % 3) * 32;
        int tx = tid & 31, ty4 = tid >> 5;
        #pragma unroll
        for (int r = 0; r < 4; ++r) {
            int ty = ty4 + r * 8;
            int i = i0 + ty, c = c0 + tx;
            tile[ty][tx] = (i < NP && c < NC) ? logits[((size_t)img * NP + i) * NC + c] : 0.f;
        }
        __syncthreads();
        #pragma unroll
        for (int r = 0; r < 4; ++r) {
            int ty = ty4 + r * 8;
            int c = c0 + ty, i = i0 + tx;
            if (c < NC && i < NP) logT[((size_t)img * NC + c) * NP + i] = tile[tx][ty];
        }
    } else if (blk < 1920) {
        int rel = blk - 1856;
        int img = rel >> 2, q = rel & 3;
        int i = q * 256 + tid;
        if (i >= NP) return;
        const float* lr = logits + ((size_t)img * NP + i) * NC;
        float s = 0.f;
        #pragma unroll 4
        for (int c = 0; c < NC; ++c) {
            float x = lr[c];
            float p = 1.f / (1.f + expf(-x));
            float ax = fabsf(x);
            float sp = log1pf(expf(-ax));
            float ls_neg = fminf(-x, 0.f) - sp;
            s += 0.75f * (-ls_neg) * p * p;
        }
        negsum[img * NP + i] = s;
    } else if (blk < 2045) {
        int idx = (blk - 1920) * 256 + tid;
        if (idx < 16000) interA[idx] = 0.f;
        else if (idx < 32000) msumA[idx - 16000] = 0.f;
    } else {
        if (tid < 80) accum[tid] = 0.f;
        else if (tid < 160) cnt[tid - 80] = 0;
    }
}

// ======= cost column + per-wave register top-k (one wave per column) =======
__global__ void __launch_bounds__(256) k_costtopk(
        const float* __restrict__ logT, const float* __restrict__ boxes,
        const float* __restrict__ gtb, const int* __restrict__ gcls_all,
        const float* __restrict__ imsz,
        const int* __restrict__ valid, const unsigned long long* __restrict__ inboth,
        const int* __restrict__ hasvalid,
        float* __restrict__ cost, float* __restrict__ kthc, int* __restrict__ kthi) {
    int img = blockIdx.y, b = img % BATCH;
    int tid = threadIdx.x;
    int w = tid >> 6, l = tid & 63;
    int j = blockIdx.x * 4 + w;
    float s = imsz[b], inv_s = 1.f / s;
    const float* gj = gtb + (b * NM + j) * 4;
    float gx0 = gj[0], gy0 = gj[1], gx1 = gj[2], gy1 = gj[3];
    int gc = gcls_all[b * NM + j];
    int hv = hasvalid[img];
    float garea = (gx1 - gx0) * (gy1 - gy0);
    float ngx0 = gx0 * inv_s, ngy0 = gy0 * inv_s, ngx1 = gx1 * inv_s, ngy1 = gy1 * inv_s;
    float ngarea = (ngx1 - ngx0) * (ngy1 - ngy0);
    size_t colbase = ((size_t)img * NM + j) * NP;
    const float* lrow = logT + ((size_t)img * NC + gc) * NP;
    float icv[16], ccv[16];
    #pragma unroll
    for (int e = 0; e < 16; ++e) {
        int i = e * 64 + l;
        if (i < NP) {
            float4 bx = *(const float4*)&boxes[((size_t)img * NP + i) * 4];
            float x0 = bx.x, y0 = bx.y, x1 = bx.z, y1 = bx.w;
            float area = (x1 - x0) * (y1 - y0);
            float ltx = fmaxf(x0, gx0), lty = fmaxf(y0, gy0);
            float rbx = fminf(x1, gx1), rby = fminf(y1, gy1);
            float iw = fmaxf(rbx - ltx, 0.f), ih = fmaxf(rby - lty, 0.f);
            float inter = iw * ih;
            float uni = fmaxf(area + garea - inter, 1e-8f);
            float iou = inter / uni;
            float nx0 = x0 * inv_s, ny0 = y0 * inv_s, nx1 = x1 * inv_s, ny1 = y1 * inv_s;
            float narea = (nx1 - nx0) * (ny1 - ny0);
            float nltx = fmaxf(nx0, ngx0), nlty = fmaxf(ny0, ngy0);
            float nrbx = fminf(nx1, ngx1), nrby = fminf(ny1, ngy1);
            float niw = fmaxf(nrbx - nltx, 0.f), nih = fmaxf(nrby - nlty, 0.f);
            float ninter = niw * nih;
            float nuni = narea + ngarea - ninter;
            float niou = ninter / nuni;
            float ex0 = fminf(nx0, ngx0), ey0 = fminf(ny0, ngy0);
            float ex1 = fmaxf(nx1, ngx1), ey1 = fmaxf(ny1, ngy1);
            float earea = fmaxf(ex1 - ex0, 0.f) * fmaxf(ey1 - ey0, 0.f);
            float giou = niou - (earea - nuni) / earea;
            float giou_cost = 2.f * (1.f - giou);
            float l1 = 5.f * (fabsf(nx0 - ngx0) + fabsf(ny0 - ngy0) + fabsf(nx1 - ngx1) + fabsf(ny1 - ngy1));
            float x = lrow[i];
            float p = 1.f / (1.f + expf(-x));
            float neg = -logf(1.f - p + 1e-8f) * 0.75f * p * p;
            float pos = -logf(p + 1e-8f) * 0.25f * (1.f - p) * (1.f - p);
            float cls = 2.f * (pos - neg);
            bool vld = (valid[img * NP + i] != 0) || (hv == 0);
            bool inb = (((inboth[img * NP + i] >> j) & 1ull) != 0ull) || (hv == 0);
            float cst = cls + l1 + giou_cost + (inb ? 0.f : 100000.f);
            if (!vld) cst = 1e15f;
            cost[colbase + i] = cst;
            ccv[e] = cst;
            icv[e] = vld ? iou : 0.f;
        } else {
            ccv[e] = FLT_MAX;
            icv[e] = -FLT_MAX;
        }
    }
    unsigned cons = 0;
    float ssum = 0.f;
    for (int it = 0; it < 10; ++it) {
        float bv = -FLT_MAX; int bi = 0x7fffffff;
        #pragma unroll
        for (int e = 0; e < 16; ++e) {
            if (cons & (1u << e)) continue;
            float v = icv[e]; int i = e * 64 + l;
            if ((v > bv) || (v == bv && i < bi)) { bv = v; bi = i; }
        }
        #pragma unroll
        for (int sft = 1; sft < 64; sft <<= 1) {
            float ov = __shfl_xor(bv, sft, 64);
            int oi = __shfl_xor(bi, sft, 64);
            if ((ov > bv) || (ov == bv && oi < bi)) { bv = ov; bi = oi; }
        }
        ssum += bv;
        if ((bi & 63) == l) cons |= 1u << (bi >> 6);
    }
    int dk = (int)ssum; if (dk < 1) dk = 1;
    cons = 0;
    float gv = 0.f; int gi = 0;
    for (int it = 0; it < dk; ++it) {
        float bv = FLT_MAX; int bi = 0x7fffffff;
        #pragma unroll
        for (int e = 0; e < 16; ++e) {
            if (cons & (1u << e)) continue;
            float v = ccv[e]; int i = e * 64 + l;
            if ((v < bv) || (v == bv && i < bi)) { bv = v; bi = i; }
        }
        #pragma unroll
        for (int sft = 1; sft < 64; sft <<= 1) {
            float ov = __shfl_xor(bv, sft, 64);
            int oi = __shfl_xor(bi, sft, 64);
            if ((ov < bv) || (ov == bv && oi < bi)) { bv = ov; bi = oi; }
        }
        if ((bi & 63) == l) cons |= 1u << (bi >> 6);
        gv = bv; gi = bi;
    }
    if (l == 0) { kthc[img * NM + j] = gv; kthi[img * NM + j] = gi; }
}

// ======= matching + l1/giou + fused focal (negsum + fg correction) =======
__global__ void k_match(const float* __restrict__ cost,
                        const float* __restrict__ kthc, const int* __restrict__ kthi,
                        const float* __restrict__ boxes, const float* __restrict__ gtb,
                        const float* __restrict__ imsz, const int* __restrict__ gcls_all,
                        const float* __restrict__ negsum, const float* __restrict__ logT,
                        int* __restrict__ fg, int* __restrict__ gt_ind,
                        int* __restrict__ cnt, float* __restrict__ accum) {
    int img = blockIdx.y, b = img % BATCH;
    int i = blockIdx.x * blockDim.x + threadIdx.x;
    __shared__ float skc[NM]; __shared__ int ski[NM];
    __shared__ float red[256];
    if (threadIdx.x < NM) {
        skc[threadIdx.x] = kthc[img * NM + threadIdx.x];
        ski[threadIdx.x] = kthi[img * NM + threadIdx.x];
    }
    __syncthreads();
    float l1 = 0.f, gl = 0.f, f = 0.f, vcls = 0.f;
    if (i < NP) {
        vcls = negsum[img * NP + i];
        int cntm = 0, first = -1;
        float bc = FLT_MAX; int bj = 0;
        for (int j = 0; j < NM; ++j) {
            float c = cost[((size_t)img * NM + j) * NP + i];
            bool m = (c < skc[j]) || (c == skc[j] && i <= ski[j]);
            if (m) { cntm++; if (first < 0) first = j; }
            if (c < bc) { bc = c; bj = j; }
        }
        int gi = 0, isfg = 0;
        if (cntm > 1) { gi = bj; isfg = 1; }
        else if (cntm == 1) { gi = first; isfg = 1; }
        fg[img * NP + i] = isfg;
        gt_ind[img * NP + i] = gi;
        if (isfg) {
            int gc = gcls_all[b * NM + gi];
            atomicAdd(&cnt[gc], 1);
            float x = logT[((size_t)img * NC + gc) * NP + i];
            float p = 1.f / (1.f + expf(-x));
            float ax = fabsf(x);
            float sp = log1pf(expf(-ax));
            float ls_pos = fminf(x, 0.f) - sp;
            float ls_neg = fminf(-x, 0.f) - sp;
            float pos = 0.25f * (-ls_pos) * (1.f - p) * (1.f - p);
            float neg = 0.75f * (-ls_neg) * p * p;
            vcls += pos - neg;
            float inv = 1.f / imsz[b];
            float4 bx = *(const float4*)&boxes[((size_t)img * NP + i) * 4];
            const float* gj = gtb + (b * NM + gi) * 4;
            float nx0 = bx.x*inv, ny0 = bx.y*inv, nx1 = bx.z*inv, ny1 = bx.w*inv;
            float gx0 = gj[0]*inv, gy0 = gj[1]*inv, gx1 = gj[2]*inv, gy1 = gj[3]*inv;
            l1 = fabsf(nx0-gx0) + fabsf(ny0-gy0) + fabsf(nx1-gx1) + fabsf(ny1-gy1);
            float a1 = (nx1-nx0)*(ny1-ny0), a2 = (gx1-gx0)*(gy1-gy0);
            float ltx = fmaxf(nx0,gx0), lty = fmaxf(ny0,gy0);
            float rbx = fminf(nx1,gx1), rby = fminf(ny1,gy1);
            float iw = fmaxf(rbx-ltx,0.f), ih = fmaxf(rby-lty,0.f);
            float inter = iw*ih, uni = a1+a2-inter, iou = inter/uni;
            float ex0 = fminf(nx0,gx0), ey0 = fminf(ny0,gy0);
            float ex1 = fmaxf(nx1,gx1), ey1 = fmaxf(ny1,gy1);
            float ea = fmaxf(ex1-ex0,0.f)*fmaxf(ey1-ey0,0.f);
            float giou = iou - (ea-uni)/ea;
            gl = 1.f - giou;
            f = 1.f;
        }
    }
    float scl = block_reduce_sum(vcls, red);
    float sl1 = block_reduce_sum(l1, red);
    float sgl = block_reduce_sum(gl, red);
    float sf  = block_reduce_sum(f, red);
    if (threadIdx.x == 0) {
        atomicAdd(&accum[img*5+0], scl);
        atomicAdd(&accum[img*5+1], sl1);
        atomicAdd(&accum[img*5+2], sgl);
        atomicAdd(&accum[img*5+4], sf);
    }
}

// ==== scan + XCD-aware chunk table (class c -> slots ≡ c mod 8) + scatter ====
__global__ void __launch_bounds__(1024) k_scanscatter(
        const int* __restrict__ cnt, const int* __restrict__ fg,
        const int* __restrict__ gti, const int* __restrict__ gcls,
        int* __restrict__ offs_g, int* __restrict__ total,
        int* __restrict__ chtab, int* __restrict__ list) {
    __shared__ int offs[NC]; __shared__ int sfill[NC];
    __shared__ int schtab[MAXCH]; __shared__ int ovf[MAXCH];
    int tid = threadIdx.x;
    if (tid < MAXCH) { schtab[tid] = -1; ovf[tid] = -1; }
    if (tid < NC) sfill[tid] = 0;
    __syncthreads();
    if (tid == 0) {
        int s = 0;
        for (int c = 0; c < NC; ++c) { offs[c] = s; s += cnt[c]; }
        *total = s;
        int xcnt[8] = {0, 0, 0, 0, 0, 0, 0, 0};
        int ocnt = 0;
        const int SLOTS_PER_XCD = MAXCH / 8;   // 96
        for (int c = 0; c < NC; ++c) {
            int nchc = (cnt[c] + CH - 1) / CH;
            int r = c & 7;
            for (int k = 0; k < nchc; ++k) {
                int ent = (c << 16) | k;
                if (xcnt[r] < SLOTS_PER_XCD) {
                    schtab[r + 8 * xcnt[r]] = ent;
                    xcnt[r]++;
                } else {
                    ovf[ocnt++] = ent;
                }
            }
        }
        int pos = 0;
        for (int o = 0; o < ocnt; ++o) {
            while (schtab[pos] >= 0) pos++;
            schtab[pos] = ovf[o];
        }
    }
    __syncthreads();
    if (tid < MAXCH) chtab[tid] = schtab[tid];
    if (tid < NC) offs_g[tid] = offs[tid];
    for (int idx = tid; idx < NIMG * NP; idx += 1024) {
        if (fg[idx]) {
            int img = idx / NP, i = idx % NP, b = img % BATCH;
            int gt = gti[idx];
            int c = gcls[b * NM + gt];
            int pos = offs[c] + atomicAdd(&sfill[c], 1);
            list[pos] = (img << 16) | (gt << 10) | i;
        }
    }
}

// ---- R10 mask GEMM (ring-4 register prefetch), XCD-swizzled chunk table ----
__global__ void __launch_bounds__(128) k_mgemm(
        const float* __restrict__ pfeat, const float* __restrict__ wmask,
        const float* __restrict__ gtm, const int* __restrict__ list,
        const int* __restrict__ cnt, const int* __restrict__ offs,
        const int* __restrict__ chtab,
        float* __restrict__ inter, float* __restrict__ msum) {
    int e = chtab[blockIdx.x];
    if (e < 0) return;
    int c = e >> 16, k = e & 0xffff;
    int base = offs[c] + k * CH;
    int P = min(CH, cnt[c] - k * CH);
    int tid = threadIdx.x;
    bool act = (tid < TPT);
    int t = blockIdx.y * TPT + (act ? tid : 0);
    __shared__ float pf[CH][ND];
    __shared__ int sl[CH];
    if (tid < CH) sl[tid] = (tid < P) ? list[base + tid] : 0;
    __syncthreads();
    for (int idx = tid; idx < CH * (ND / 4); idx += 128) {
        int p = idx >> 6, d4 = idx & 63;
        float4 v = {0.f, 0.f, 0.f, 0.f};
        if (p < P) {
            int pk = sl[p];
            int img = pk >> 16, i = pk & 1023;
            v = *(const float4*)&pfeat[((size_t)img * NP + i) * ND + d4 * 4];
        }
        *(float4*)&pf[p][d4 * 4] = v;
    }
    __syncthreads();
    float acc[CH];
    #pragma unroll
    for (int p = 0; p < CH; ++p) acc[p] = 0.f;
    if (act) {
        const float* wr = wmask + (size_t)c * TT + t;
        float4 wq[4];
        #pragma unroll
        for (int q = 0; q < 4; ++q) {
            const float* wp = wr + (size_t)q * 4 * CWTT;
            wq[q].x = wp[0]; wq[q].y = wp[CWTT];
            wq[q].z = wp[2 * (size_t)CWTT]; wq[q].w = wp[3 * (size_t)CWTT];
        }
        #pragma unroll 4
        for (int d4 = 0; d4 < 60; ++d4) {
            float4 w = wq[d4 & 3];
            const float* wp = wr + (size_t)(d4 + 4) * 4 * CWTT;
            wq[d4 & 3].x = wp[0]; wq[d4 & 3].y = wp[CWTT];
            wq[d4 & 3].z = wp[2 * (size_t)CWTT]; wq[d4 & 3].w = wp[3 * (size_t)CWTT];
            int d = d4 * 4;
            #pragma unroll
            for (int p = 0; p < CH; ++p) {
                float4 q4 = *(const float4*)&pf[p][d];
                acc[p] += q4.x * w.x + q4.y * w.y + q4.z * w.z + q4.w * w.w;
            }
        }
        #pragma unroll
        for (int d4 = 60; d4 < 64; ++d4) {
            float4 w = wq[d4 & 3];
            int d = d4 * 4;
            #pragma unroll
            for (int p = 0; p < CH; ++p) {
                float4 q4 = *(const float4*)&pf[p][d];
                acc[p] += q4.x * w.x + q4.y * w.y + q4.z * w.z + q4.w * w.w;
            }
        }
    }
    #pragma unroll 4
    for (int p = 0; p < CH; ++p) {
        if (p >= P) break;
        int pk = sl[p];
        int img = pk >> 16, j = (pk >> 10) & 63, b = img % BATCH;
        float li = 0.f, lm = 0.f;
        if (act) {
            float m = 1.f / (1.f + expf(-acc[p]));
            float g = gtm[((size_t)(b * NM + j)) * TT + t];
            li = m * g; lm = m;
        }
        #pragma unroll
        for (int s = 32; s > 0; s >>= 1) {
            li += __shfl_down(li, s, 64);
            lm += __shfl_down(lm, s, 64);
        }
        if ((tid & 63) == 0) {
            atomicAdd(&inter[base + p], li);
            atomicAdd(&msum[base + p], lm);
        }
    }
}

// ---------------- dice + final, single block ----------------
__global__ void __launch_bounds__(256) k_dicefinal(
        const int* __restrict__ list, const int* __restrict__ total,
        const float* __restrict__ inter, const float* __restrict__ msum,
        const float* __restrict__ gmsum, const float* __restrict__ accum,
        float* __restrict__ out) {
    __shared__ float md[NIMG];
    int tid = threadIdx.x;
    if (tid < NIMG) md[tid] = 0.f;
    __syncthreads();
    int n = *total;
    for (int e = tid; e < n; e += 256) {
        int pk = list[e];
        int img = pk >> 16, j = (pk >> 10) & 63, b = img % BATCH;
        float d = 1.f - 2.f * inter[e] / (msum[e] + gmsum[b * NM + j] + 1e-8f);
        atomicAdd(&md[img], d);
    }
    __syncthreads();
    if (tid == 0) {
        float tot[4] = {0.f, 0.f, 0.f, 0.f};
        for (int l = 0; l < LOUT; ++l) {
            float s0 = 0.f, s1 = 0.f, s2 = 0.f, s3 = 0.f, s4 = 0.f;
            for (int b = 0; b < BATCH; ++b) {
                int img = l * BATCH + b;
                s0 += accum[img*5+0]; s1 += accum[img*5+1]; s2 += accum[img*5+2];
                s3 += md[img];        s4 += accum[img*5+4];
            }
            tot[0] += s0 / s4; tot[1] += s1 / s4; tot[2] += s2 / s4; tot[3] += s3 / s4;
        }
        const float w[4] = {2.f, 5.f, 2.f, 5.f};
        for (int k = 0; k < 4; ++k) out[k] = w[k] * tot[k] / (float)LOUT;
    }
}

extern "C" void kernel_launch(void* const* d_in, const int* in_sizes, int n_in,
                              void* d_out, int out_size, void* d_ws, size_t ws_size,
                              hipStream_t stream) {
    const float* logits = (const float*)d_in[0];
    const float* boxes  = (const float*)d_in[1];
    const float* pfeat  = (const float*)d_in[2];
    const float* gtb    = (const float*)d_in[3];
    const float* gtm    = (const float*)d_in[4];
    const float* imsz   = (const float*)d_in[5];
    const float* wmask  = (const float*)d_in[6];
    const int*   gcls   = (const int*)d_in[7];

    char* ws = (char*)d_ws;
    size_t off = 0;
    auto alloc = [&](size_t bytes) -> void* {
        void* p = ws + off;
        off = (off + bytes + 255) & ~(size_t)255;
        return p;
    };
    int* hasvalid = (int*)alloc(NIMG * sizeof(int));
    // zeroed inside k_prep (consumers are later dispatches):
    float* accum = (float*)alloc(NIMG * 5 * sizeof(float));
    int* cnt    = (int*)alloc(NC * sizeof(int));
    float* interA = (float*)alloc((size_t)MAXF * sizeof(float));
    float* msumA  = (float*)alloc((size_t)MAXF * sizeof(float));
    // uninitialized scratch:
    float* cost = (float*)alloc((size_t)NIMG * NM * NP * sizeof(float));
    float* logT = (float*)alloc((size_t)NIMG * NC * NP * sizeof(float));
    float* negsum = (float*)alloc((size_t)NIMG * NP * sizeof(float));
    int* valid  = (int*)alloc((size_t)NIMG * NP * sizeof(int));
    unsigned long long* inboth = (unsigned long long*)alloc((size_t)NIMG * NP * sizeof(unsigned long long));
    float* kthc = (float*)alloc(NIMG * NM * sizeof(float));
    int* kthi   = (int*)alloc(NIMG * NM * sizeof(int));
    int* fg     = (int*)alloc((size_t)NIMG * NP * sizeof(int));
    int* gti    = (int*)alloc((size_t)NIMG * NP * sizeof(int));
    float* gmsum = (float*)alloc(BATCH * NM * sizeof(float));
    int* offs   = (int*)alloc(NC * sizeof(int));
    int* total  = (int*)alloc(sizeof(int));
    int* chtab  = (int*)alloc((size_t)MAXCH * sizeof(int));
    int* list   = (int*)alloc((size_t)MAXF * sizeof(int));

    hipMemsetAsync(hasvalid, 0, NIMG * sizeof(int), stream);

    k_prep<<<2046, 256, 0, stream>>>(logits, boxes, gtb, gtm, valid, inboth, hasvalid,
                                     logT, negsum, gmsum, interA, msumA, accum, cnt);
    k_costtopk<<<dim3(NM / 4, NIMG), 256, 0, stream>>>(logT, boxes, gtb, gcls, imsz, valid, inboth, hasvalid, cost, kthc, kthi);
    k_match<<<dim3((NP + 255) / 256, NIMG), 256, 0, stream>>>(cost, kthc, kthi, boxes, gtb, imsz, gcls, negsum, logT, fg, gti, cnt, accum);
    k_scanscatter<<<1, 1024, 0, stream>>>(cnt, fg, gti, gcls, offs, total, chtab, list);
    k_mgemm<<<dim3(MAXCH, 7), 128, 0, stream>>>(pfeat, wmask, gtm, list, cnt, offs, chtab, interA, msumA);
    k_dicefinal<<<1, 256, 0, stream>>>(list, total, interA, msumA, gmsum, accum, (float*)d_out);
}

// Round 13
// 193.016 us; speedup vs baseline: 1.2904x; 1.2904x over previous
//
#include <hip/hip_runtime.h>
#include <math.h>
#include <float.h>

#define LOUT 4
#define BATCH 4
#define NP 1000
#define NC 80
#define NM 64
#define ND 256
#define TT 784
#define NIMG (LOUT*BATCH)
#define CWTT (NC*TT)   // 62720
#define MAXF (NIMG*NP) // 16000
#define CH 16          // priors per chunk
#define TPT 112        // t-values per tile (7*112 = 784)
#define MAXCH 768      // >= 10240/16 + 80

__device__ __forceinline__ float block_reduce_sum(float v, float* red) {
    int tid = threadIdx.x;
    red[tid] = v; __syncthreads();
    for (int s = blockDim.x >> 1; s > 0; s >>= 1) {
        if (tid < s) red[tid] += red[tid + s];
        __syncthreads();
    }
    float r = red[0]; __syncthreads();
    return r;
}

// ============ fused prep: gmsum | valid | logT | negsum | zeroing ============
__global__ void __launch_bounds__(256) k_prep(
        const float* __restrict__ logits, const float* __restrict__ boxes,
        const float* __restrict__ gtb, const float* __restrict__ gtm,
        int* __restrict__ valid, unsigned long long* __restrict__ inboth,
        float* __restrict__ logT, float* __restrict__ negsum,
        float* __restrict__ gmsum, float* __restrict__ interA,
        float* __restrict__ msumA, float* __restrict__ accum, int* __restrict__ cnt) {
    int blk = blockIdx.x;
    int tid = threadIdx.x;
    __shared__ float red[256];
    __shared__ float tile[32][33];
    if (blk < 256) {
        int bj = blk;
        float s = 0.f;
        for (int t = tid; t < TT; t += 256) s += gtm[(size_t)bj * TT + t];
        float r = block_reduce_sum(s, red);
        if (tid == 0) gmsum[bj] = r;
    } else if (blk < 320) {
        int rel = blk - 256;
        int img = rel >> 2, q = rel & 3, b = img % BATCH;
        float* g = red;
        g[tid] = gtb[b * NM * 4 + tid];
        __syncthreads();
        int i = q * 256 + tid;
        if (i >= NP) return;
        float4 bx = *(const float4*)&boxes[((size_t)img * NP + i) * 4];
        float x0 = bx.x, y0 = bx.y, x1 = bx.z, y1 = bx.w;
        float cx = (x0 + x1) * 0.5f, cy = (y0 + y1) * 0.5f;
        float w = x1 - x0, h = y1 - y0;
        float rx = 2.5f * w, ry = 2.5f * h;
        bool any_gt = false, any_ct = false;
        unsigned long long ib = 0ull;
        for (int j = 0; j < NM; ++j) {
            float gx0 = g[j*4], gy0 = g[j*4+1], gx1 = g[j*4+2], gy1 = g[j*4+3];
            bool igt = (cx > gx0) && (cy > gy0) && (cx < gx1) && (cy < gy1);
            float gcx = (gx0 + gx1) * 0.5f, gcy = (gy0 + gy1) * 0.5f;
            bool ict = (cx > gcx - rx) && (cx < gcx + rx) && (cy > gcy - ry) && (cy < gcy + ry);
            any_gt |= igt; any_ct |= ict;
            if (igt && ict) ib |= (1ull << j);
        }
        bool v = any_gt || any_ct;
        valid[img * NP + i] = v ? 1 : 0;
        inboth[img * NP + i] = ib;
    } else if (blk < 1856) {
        int rel = blk - 320;
        int img = rel / 96; int r2 = rel % 96;
        int i0 = (r2 / 3) * 32, c0 = (r2 % 3) * 32;
        int tx = tid & 31, ty4 = tid >> 5;
        #pragma unroll
        for (int r = 0; r < 4; ++r) {
            int ty = ty4 + r * 8;
            int i = i0 + ty, c = c0 + tx;
            tile[ty][tx] = (i < NP && c < NC) ? logits[((size_t)img * NP + i) * NC + c] : 0.f;
        }
        __syncthreads();
        #pragma unroll
        for (int r = 0; r < 4; ++r) {
            int ty = ty4 + r * 8;
            int c = c0 + ty, i = i0 + tx;
            if (c < NC && i < NP) logT[((size_t)img * NC + c) * NP + i] = tile[tx][ty];
        }
    } else if (blk < 1920) {
        int rel = blk - 1856;
        int img = rel >> 2, q = rel & 3;
        int i = q * 256 + tid;
        if (i >= NP) return;
        const float* lr = logits + ((size_t)img * NP + i) * NC;
        float s = 0.f;
        #pragma unroll 4
        for (int c = 0; c < NC; ++c) {
            float x = lr[c];
            float p = 1.f / (1.f + expf(-x));
            float ax = fabsf(x);
            float sp = log1pf(expf(-ax));
            float ls_neg = fminf(-x, 0.f) - sp;
            s += 0.75f * (-ls_neg) * p * p;
        }
        negsum[img * NP + i] = s;
    } else if (blk < 2045) {
        int idx = (blk - 1920) * 256 + tid;
        if (idx < 16000) interA[idx] = 0.f;
        else if (idx < 32000) msumA[idx - 16000] = 0.f;
    } else {
        if (tid < 80) accum[tid] = 0.f;
        else if (tid < 160) cnt[tid - 80] = 0;
    }
}

// ======= cost column + per-wave register top-k (one wave per column) =======
// hv computed in-register: each wave touches all 1000 valid flags (16/lane).
__global__ void __launch_bounds__(256) k_costtopk(
        const float* __restrict__ logT, const float* __restrict__ boxes,
        const float* __restrict__ gtb, const int* __restrict__ gcls_all,
        const float* __restrict__ imsz,
        const int* __restrict__ valid, const unsigned long long* __restrict__ inboth,
        float* __restrict__ cost, float* __restrict__ kthc, int* __restrict__ kthi) {
    int img = blockIdx.y, b = img % BATCH;
    int tid = threadIdx.x;
    int w = tid >> 6, l = tid & 63;
    int j = blockIdx.x * 4 + w;
    float s = imsz[b], inv_s = 1.f / s;
    const float* gj = gtb + (b * NM + j) * 4;
    float gx0 = gj[0], gy0 = gj[1], gx1 = gj[2], gy1 = gj[3];
    int gc = gcls_all[b * NM + j];
    float garea = (gx1 - gx0) * (gy1 - gy0);
    float ngx0 = gx0 * inv_s, ngy0 = gy0 * inv_s, ngx1 = gx1 * inv_s, ngy1 = gy1 * inv_s;
    float ngarea = (ngx1 - ngx0) * (ngy1 - ngy0);
    size_t colbase = ((size_t)img * NM + j) * NP;
    const float* lrow = logT + ((size_t)img * NC + gc) * NP;
    // pass 0: gather valid + inboth bits; derive hv without global hasvalid
    unsigned vmask = 0, ibmask = 0;
    #pragma unroll
    for (int e = 0; e < 16; ++e) {
        int i = e * 64 + l;
        if (i < NP) {
            if (valid[img * NP + i]) vmask |= 1u << e;
            if ((inboth[img * NP + i] >> j) & 1ull) ibmask |= 1u << e;
        }
    }
    int hv = __any(vmask != 0);
    float icv[16], ccv[16];
    #pragma unroll
    for (int e = 0; e < 16; ++e) {
        int i = e * 64 + l;
        if (i < NP) {
            float4 bx = *(const float4*)&boxes[((size_t)img * NP + i) * 4];
            float x0 = bx.x, y0 = bx.y, x1 = bx.z, y1 = bx.w;
            float area = (x1 - x0) * (y1 - y0);
            float ltx = fmaxf(x0, gx0), lty = fmaxf(y0, gy0);
            float rbx = fminf(x1, gx1), rby = fminf(y1, gy1);
            float iw = fmaxf(rbx - ltx, 0.f), ih = fmaxf(rby - lty, 0.f);
            float inter = iw * ih;
            float uni = fmaxf(area + garea - inter, 1e-8f);
            float iou = inter / uni;
            float nx0 = x0 * inv_s, ny0 = y0 * inv_s, nx1 = x1 * inv_s, ny1 = y1 * inv_s;
            float narea = (nx1 - nx0) * (ny1 - ny0);
            float nltx = fmaxf(nx0, ngx0), nlty = fmaxf(ny0, ngy0);
            float nrbx = fminf(nx1, ngx1), nrby = fminf(ny1, ngy1);
            float niw = fmaxf(nrbx - nltx, 0.f), nih = fmaxf(nrby - nlty, 0.f);
            float ninter = niw * nih;
            float nuni = narea + ngarea - ninter;
            float niou = ninter / nuni;
            float ex0 = fminf(nx0, ngx0), ey0 = fminf(ny0, ngy0);
            float ex1 = fmaxf(nx1, ngx1), ey1 = fmaxf(ny1, ngy1);
            float earea = fmaxf(ex1 - ex0, 0.f) * fmaxf(ey1 - ey0, 0.f);
            float giou = niou - (earea - nuni) / earea;
            float giou_cost = 2.f * (1.f - giou);
            float l1 = 5.f * (fabsf(nx0 - ngx0) + fabsf(ny0 - ngy0) + fabsf(nx1 - ngx1) + fabsf(ny1 - ngy1));
            float x = lrow[i];
            float p = 1.f / (1.f + expf(-x));
            float neg = -logf(1.f - p + 1e-8f) * 0.75f * p * p;
            float pos = -logf(p + 1e-8f) * 0.25f * (1.f - p) * (1.f - p);
            float cls = 2.f * (pos - neg);
            bool vld = ((vmask >> e) & 1u) || (hv == 0);
            bool inb = ((ibmask >> e) & 1u) || (hv == 0);
            float cst = cls + l1 + giou_cost + (inb ? 0.f : 100000.f);
            if (!vld) cst = 1e15f;
            cost[colbase + i] = cst;
            ccv[e] = cst;
            icv[e] = vld ? iou : 0.f;
        } else {
            ccv[e] = FLT_MAX;
            icv[e] = -FLT_MAX;
        }
    }
    unsigned cons = 0;
    float ssum = 0.f;
    for (int it = 0; it < 10; ++it) {
        float bv = -FLT_MAX; int bi = 0x7fffffff;
        #pragma unroll
        for (int e = 0; e < 16; ++e) {
            if (cons & (1u << e)) continue;
            float v = icv[e]; int i = e * 64 + l;
            if ((v > bv) || (v == bv && i < bi)) { bv = v; bi = i; }
        }
        #pragma unroll
        for (int sft = 1; sft < 64; sft <<= 1) {
            float ov = __shfl_xor(bv, sft, 64);
            int oi = __shfl_xor(bi, sft, 64);
            if ((ov > bv) || (ov == bv && oi < bi)) { bv = ov; bi = oi; }
        }
        ssum += bv;
        if ((bi & 63) == l) cons |= 1u << (bi >> 6);
    }
    int dk = (int)ssum; if (dk < 1) dk = 1;
    cons = 0;
    float gv = 0.f; int gi = 0;
    for (int it = 0; it < dk; ++it) {
        float bv = FLT_MAX; int bi = 0x7fffffff;
        #pragma unroll
        for (int e = 0; e < 16; ++e) {
            if (cons & (1u << e)) continue;
            float v = ccv[e]; int i = e * 64 + l;
            if ((v < bv) || (v == bv && i < bi)) { bv = v; bi = i; }
        }
        #pragma unroll
        for (int sft = 1; sft < 64; sft <<= 1) {
            float ov = __shfl_xor(bv, sft, 64);
            int oi = __shfl_xor(bi, sft, 64);
            if ((ov < bv) || (ov == bv && oi < bi)) { bv = ov; bi = oi; }
        }
        if ((bi & 63) == l) cons |= 1u << (bi >> 6);
        gv = bv; gi = bi;
    }
    if (l == 0) { kthc[img * NM + j] = gv; kthi[img * NM + j] = gi; }
}

// ======= matching + l1/giou + fused focal (negsum + fg correction) =======
__global__ void k_match(const float* __restrict__ cost,
                        const float* __restrict__ kthc, const int* __restrict__ kthi,
                        const float* __restrict__ boxes, const float* __restrict__ gtb,
                        const float* __restrict__ imsz, const int* __restrict__ gcls_all,
                        const float* __restrict__ negsum, const float* __restrict__ logT,
                        int* __restrict__ fg, int* __restrict__ gt_ind,
                        int* __restrict__ cnt, float* __restrict__ accum) {
    int img = blockIdx.y, b = img % BATCH;
    int i = blockIdx.x * blockDim.x + threadIdx.x;
    __shared__ float skc[NM]; __shared__ int ski[NM];
    __shared__ float red[256];
    if (threadIdx.x < NM) {
        skc[threadIdx.x] = kthc[img * NM + threadIdx.x];
        ski[threadIdx.x] = kthi[img * NM + threadIdx.x];
    }
    __syncthreads();
    float l1 = 0.f, gl = 0.f, f = 0.f, vcls = 0.f;
    if (i < NP) {
        vcls = negsum[img * NP + i];
        int cntm = 0, first = -1;
        float bc = FLT_MAX; int bj = 0;
        for (int j = 0; j < NM; ++j) {
            float c = cost[((size_t)img * NM + j) * NP + i];
            bool m = (c < skc[j]) || (c == skc[j] && i <= ski[j]);
            if (m) { cntm++; if (first < 0) first = j; }
            if (c < bc) { bc = c; bj = j; }
        }
        int gi = 0, isfg = 0;
        if (cntm > 1) { gi = bj; isfg = 1; }
        else if (cntm == 1) { gi = first; isfg = 1; }
        fg[img * NP + i] = isfg;
        gt_ind[img * NP + i] = gi;
        if (isfg) {
            int gc = gcls_all[b * NM + gi];
            atomicAdd(&cnt[gc], 1);
            float x = logT[((size_t)img * NC + gc) * NP + i];
            float p = 1.f / (1.f + expf(-x));
            float ax = fabsf(x);
            float sp = log1pf(expf(-ax));
            float ls_pos = fminf(x, 0.f) - sp;
            float ls_neg = fminf(-x, 0.f) - sp;
            float pos = 0.25f * (-ls_pos) * (1.f - p) * (1.f - p);
            float neg = 0.75f * (-ls_neg) * p * p;
            vcls += pos - neg;
            float inv = 1.f / imsz[b];
            float4 bx = *(const float4*)&boxes[((size_t)img * NP + i) * 4];
            const float* gj = gtb + (b * NM + gi) * 4;
            float nx0 = bx.x*inv, ny0 = bx.y*inv, nx1 = bx.z*inv, ny1 = bx.w*inv;
            float gx0 = gj[0]*inv, gy0 = gj[1]*inv, gx1 = gj[2]*inv, gy1 = gj[3]*inv;
            l1 = fabsf(nx0-gx0) + fabsf(ny0-gy0) + fabsf(nx1-gx1) + fabsf(ny1-gy1);
            float a1 = (nx1-nx0)*(ny1-ny0), a2 = (gx1-gx0)*(gy1-gy0);
            float ltx = fmaxf(nx0,gx0), lty = fmaxf(ny0,gy0);
            float rbx = fminf(nx1,gx1), rby = fminf(ny1,gy1);
            float iw = fmaxf(rbx-ltx,0.f), ih = fmaxf(rby-lty,0.f);
            float inter = iw*ih, uni = a1+a2-inter, iou = inter/uni;
            float ex0 = fminf(nx0,gx0), ey0 = fminf(ny0,gy0);
            float ex1 = fmaxf(nx1,gx1), ey1 = fmaxf(ny1,gy1);
            float ea = fmaxf(ex1-ex0,0.f)*fmaxf(ey1-ey0,0.f);
            float giou = iou - (ea-uni)/ea;
            gl = 1.f - giou;
            f = 1.f;
        }
    }
    float scl = block_reduce_sum(vcls, red);
    float sl1 = block_reduce_sum(l1, red);
    float sgl = block_reduce_sum(gl, red);
    float sf  = block_reduce_sum(f, red);
    if (threadIdx.x == 0) {
        atomicAdd(&accum[img*5+0], scl);
        atomicAdd(&accum[img*5+1], sl1);
        atomicAdd(&accum[img*5+2], sgl);
        atomicAdd(&accum[img*5+4], sf);
    }
}

// single block, 1024 threads: prefix-scan + chunk table + scatter (LDS fill)
__global__ void __launch_bounds__(1024) k_scanscatter(
        const int* __restrict__ cnt, const int* __restrict__ fg,
        const int* __restrict__ gti, const int* __restrict__ gcls,
        int* __restrict__ offs_g, int* __restrict__ total,
        int* __restrict__ chtab, int* __restrict__ nch, int* __restrict__ list) {
    __shared__ int offs[NC]; __shared__ int choff[NC]; __shared__ int sfill[NC];
    int tid = threadIdx.x;
    if (tid == 0) {
        int s = 0, m = 0;
        for (int c = 0; c < NC; ++c) {
            offs[c] = s; s += cnt[c];
            choff[c] = m; m += (cnt[c] + CH - 1) / CH;
        }
        *total = s; *nch = m;
    }
    if (tid < NC) sfill[tid] = 0;
    __syncthreads();
    if (tid < NC) {
        offs_g[tid] = offs[tid];
        int n = cnt[tid], co = choff[tid];
        for (int k = 0; k * CH < n; ++k) chtab[co + k] = (tid << 16) | k;
    }
    for (int idx = tid; idx < NIMG * NP; idx += 1024) {
        if (fg[idx]) {
            int img = idx / NP, i = idx % NP, b = img % BATCH;
            int gt = gti[idx];
            int c = gcls[b * NM + gt];
            int pos = offs[c] + atomicAdd(&sfill[c], 1);
            list[pos] = (img << 16) | (gt << 10) | i;
        }
    }
}

// ---- R10 mask GEMM (ring-4 register prefetch), grid (MAXCH, 7), 128 thr ----
__global__ void __launch_bounds__(128) k_mgemm(
        const float* __restrict__ pfeat, const float* __restrict__ wmask,
        const float* __restrict__ gtm, const int* __restrict__ list,
        const int* __restrict__ cnt, const int* __restrict__ offs,
        const int* __restrict__ chtab, const int* __restrict__ nch,
        float* __restrict__ inter, float* __restrict__ msum) {
    int ch = blockIdx.x;
    if (ch >= *nch) return;
    int e = chtab[ch];
    int c = e >> 16, k = e & 0xffff;
    int base = offs[c] + k * CH;
    int P = min(CH, cnt[c] - k * CH);
    int tid = threadIdx.x;
    bool act = (tid < TPT);
    int t = blockIdx.y * TPT + (act ? tid : 0);
    __shared__ float pf[CH][ND];
    __shared__ int sl[CH];
    if (tid < CH) sl[tid] = (tid < P) ? list[base + tid] : 0;
    __syncthreads();
    for (int idx = tid; idx < CH * (ND / 4); idx += 128) {
        int p = idx >> 6, d4 = idx & 63;
        float4 v = {0.f, 0.f, 0.f, 0.f};
        if (p < P) {
            int pk = sl[p];
            int img = pk >> 16, i = pk & 1023;
            v = *(const float4*)&pfeat[((size_t)img * NP + i) * ND + d4 * 4];
        }
        *(float4*)&pf[p][d4 * 4] = v;
    }
    __syncthreads();
    float acc[CH];
    #pragma unroll
    for (int p = 0; p < CH; ++p) acc[p] = 0.f;
    if (act) {
        const float* wr = wmask + (size_t)c * TT + t;
        float4 wq[4];
        #pragma unroll
        for (int q = 0; q < 4; ++q) {
            const float* wp = wr + (size_t)q * 4 * CWTT;
            wq[q].x = wp[0]; wq[q].y = wp[CWTT];
            wq[q].z = wp[2 * (size_t)CWTT]; wq[q].w = wp[3 * (size_t)CWTT];
        }
        #pragma unroll 4
        for (int d4 = 0; d4 < 60; ++d4) {
            float4 w = wq[d4 & 3];
            const float* wp = wr + (size_t)(d4 + 4) * 4 * CWTT;
            wq[d4 & 3].x = wp[0]; wq[d4 & 3].y = wp[CWTT];
            wq[d4 & 3].z = wp[2 * (size_t)CWTT]; wq[d4 & 3].w = wp[3 * (size_t)CWTT];
            int d = d4 * 4;
            #pragma unroll
            for (int p = 0; p < CH; ++p) {
                float4 q4 = *(const float4*)&pf[p][d];
                acc[p] += q4.x * w.x + q4.y * w.y + q4.z * w.z + q4.w * w.w;
            }
        }
        #pragma unroll
        for (int d4 = 60; d4 < 64; ++d4) {
            float4 w = wq[d4 & 3];
            int d = d4 * 4;
            #pragma unroll
            for (int p = 0; p < CH; ++p) {
                float4 q4 = *(const float4*)&pf[p][d];
                acc[p] += q4.x * w.x + q4.y * w.y + q4.z * w.z + q4.w * w.w;
            }
        }
    }
    #pragma unroll 4
    for (int p = 0; p < CH; ++p) {
        if (p >= P) break;
        int pk = sl[p];
        int img = pk >> 16, j = (pk >> 10) & 63, b = img % BATCH;
        float li = 0.f, lm = 0.f;
        if (act) {
            float m = 1.f / (1.f + expf(-acc[p]));
            float g = gtm[((size_t)(b * NM + j)) * TT + t];
            li = m * g; lm = m;
        }
        #pragma unroll
        for (int s = 32; s > 0; s >>= 1) {
            li += __shfl_down(li, s, 64);
            lm += __shfl_down(lm, s, 64);
        }
        if ((tid & 63) == 0) {
            atomicAdd(&inter[base + p], li);
            atomicAdd(&msum[base + p], lm);
        }
    }
}

// ---------------- dice + final, single block ----------------
__global__ void __launch_bounds__(256) k_dicefinal(
        const int* __restrict__ list, const int* __restrict__ total,
        const float* __restrict__ inter, const float* __restrict__ msum,
        const float* __restrict__ gmsum, const float* __restrict__ accum,
        float* __restrict__ out) {
    __shared__ float md[NIMG];
    int tid = threadIdx.x;
    if (tid < NIMG) md[tid] = 0.f;
    __syncthreads();
    int n = *total;
    for (int e = tid; e < n; e += 256) {
        int pk = list[e];
        int img = pk >> 16, j = (pk >> 10) & 63, b = img % BATCH;
        float d = 1.f - 2.f * inter[e] / (msum[e] + gmsum[b * NM + j] + 1e-8f);
        atomicAdd(&md[img], d);
    }
    __syncthreads();
    if (tid == 0) {
        float tot[4] = {0.f, 0.f, 0.f, 0.f};
        for (int l = 0; l < LOUT; ++l) {
            float s0 = 0.f, s1 = 0.f, s2 = 0.f, s3 = 0.f, s4 = 0.f;
            for (int b = 0; b < BATCH; ++b) {
                int img = l * BATCH + b;
                s0 += accum[img*5+0]; s1 += accum[img*5+1]; s2 += accum[img*5+2];
                s3 += md[img];        s4 += accum[img*5+4];
            }
            tot[0] += s0 / s4; tot[1] += s1 / s4; tot[2] += s2 / s4; tot[3] += s3 / s4;
        }
        const float w[4] = {2.f, 5.f, 2.f, 5.f};
        for (int k = 0; k < 4; ++k) out[k] = w[k] * tot[k] / (float)LOUT;
    }
}

extern "C" void kernel_launch(void* const* d_in, const int* in_sizes, int n_in,
                              void* d_out, int out_size, void* d_ws, size_t ws_size,
                              hipStream_t stream) {
    const float* logits = (const float*)d_in[0];
    const float* boxes  = (const float*)d_in[1];
    const float* pfeat  = (const float*)d_in[2];
    const float* gtb    = (const float*)d_in[3];
    const float* gtm    = (const float*)d_in[4];
    const float* imsz   = (const float*)d_in[5];
    const float* wmask  = (const float*)d_in[6];
    const int*   gcls   = (const int*)d_in[7];

    char* ws = (char*)d_ws;
    size_t off = 0;
    auto alloc = [&](size_t bytes) -> void* {
        void* p = ws + off;
        off = (off + bytes + 255) & ~(size_t)255;
        return p;
    };
    // zeroed inside k_prep (consumers are later dispatches):
    float* accum = (float*)alloc(NIMG * 5 * sizeof(float));
    int* cnt    = (int*)alloc(NC * sizeof(int));
    float* interA = (float*)alloc((size_t)MAXF * sizeof(float));
    float* msumA  = (float*)alloc((size_t)MAXF * sizeof(float));
    // uninitialized scratch:
    float* cost = (float*)alloc((size_t)NIMG * NM * NP * sizeof(float));
    float* logT = (float*)alloc((size_t)NIMG * NC * NP * sizeof(float));
    float* negsum = (float*)alloc((size_t)NIMG * NP * sizeof(float));
    int* valid  = (int*)alloc((size_t)NIMG * NP * sizeof(int));
    unsigned long long* inboth = (unsigned long long*)alloc((size_t)NIMG * NP * sizeof(unsigned long long));
    float* kthc = (float*)alloc(NIMG * NM * sizeof(float));
    int* kthi   = (int*)alloc(NIMG * NM * sizeof(int));
    int* fg     = (int*)alloc((size_t)NIMG * NP * sizeof(int));
    int* gti    = (int*)alloc((size_t)NIMG * NP * sizeof(int));
    float* gmsum = (float*)alloc(BATCH * NM * sizeof(float));
    int* offs   = (int*)alloc(NC * sizeof(int));
    int* total  = (int*)alloc(sizeof(int));
    int* nch    = (int*)alloc(sizeof(int));
    int* chtab  = (int*)alloc((size_t)MAXCH * sizeof(int));
    int* list   = (int*)alloc((size_t)MAXF * sizeof(int));

    k_prep<<<2046, 256, 0, stream>>>(logits, boxes, gtb, gtm, valid, inboth,
                                     logT, negsum, gmsum, interA, msumA, accum, cnt);
    k_costtopk<<<dim3(NM / 4, NIMG), 256, 0, stream>>>(logT, boxes, gtb, gcls, imsz, valid, inboth, cost, kthc, kthi);
    k_match<<<dim3((NP + 255) / 256, NIMG), 256, 0, stream>>>(cost, kthc, kthi, boxes, gtb, imsz, gcls, negsum, logT, fg, gti, cnt, accum);
    k_scanscatter<<<1, 1024, 0, stream>>>(cnt, fg, gti, gcls, offs, total, chtab, nch, list);
    k_mgemm<<<dim3(MAXCH, 7), 128, 0, stream>>>(pfeat, wmask, gtm, list, cnt, offs, chtab, nch, interA, msumA);
    k_dicefinal<<<1, 256, 0, stream>>>(list, total, interA, msumA, gmsum, accum, (float*)d_out);
}